// Round 9
// baseline (170.440 us; speedup 1.0000x reference)
//
#include <hip/hip_runtime.h>

#define NTH 256
#define N_NODES 2048

// Split symmetrized coefficient tables (workspace floats).
// Half A (waves 0-1): nu3 {s0,s1,s2, s0p0,s0p1,s0p2}, nu2 {w20s0,w20s1, s0p0,s0p1},
//                     nu1 {b10, b11p0}
// Half B (waves 2-3): nu3 {s1p0..s1p2, s2p0..s2p2},   nu2 {s0p2, s1p0,s1p1,s1p2},
//                     nu1 {b11p1, b11p2}
#define G3A_OFF 0      // 165*6
#define G3B_OFF 990    // 165*6
#define G2A_OFF 1980   // 45*4
#define G2B_OFF 2160   // 45*4
#define G1A_OFF 2340   // 9*2
#define G1B_OFF 2358   // 9*2
#define TAB_FLOATS 2376

// ---------------- prep: build split symmetrized tables into global ws ----------------
__global__ void mace_prep(
    const float* __restrict__ b10, const float* __restrict__ b11,
    const float* __restrict__ b20, const float* __restrict__ b21,
    const float* __restrict__ b30, const float* __restrict__ b31,
    float* __restrict__ tab)
{
    const int tid = threadIdx.x;
    if (tid < 165) {
        // decode multiset rank -> (i<=j<=k)
        int i = 0, j = 0, k = 0;
        {
            int c = 0;
            for (int ii = 0; ii < 9; ii++)
                for (int jj = ii; jj < 9; jj++)
                    for (int kk = jj; kk < 9; kk++) {
                        if (c == tid) { i = ii; j = jj; k = kk; }
                        c++;
                    }
        }
        float s[12];
        #pragma unroll
        for (int q = 0; q < 12; q++) s[q] = 0.f;
        auto add3 = [&](int a, int b, int c2) {
            int o30 = ((a * 9 + b) * 9 + c2) * 3;   // b30: (9,9,9,3,1)
            int o31 = o30 * 3;                      // b31: (9,9,9,3,3)
            #pragma unroll
            for (int q = 0; q < 3; q++) s[q] += b30[o30 + q];
            #pragma unroll
            for (int q = 0; q < 9; q++) s[3 + q] += b31[o31 + q];
        };
        if (i == j && j == k) { add3(i, j, k); }
        else if (i == j)      { add3(i, i, k); add3(i, k, i); add3(k, i, i); }
        else if (j == k)      { add3(i, j, j); add3(j, i, j); add3(j, j, i); }
        else { add3(i,j,k); add3(i,k,j); add3(j,i,k); add3(j,k,i); add3(k,i,j); add3(k,j,i); }
        #pragma unroll
        for (int q = 0; q < 6; q++) {
            tab[G3A_OFF + tid * 6 + q] = s[q];       // s0..2, s0p0..2
            tab[G3B_OFF + tid * 6 + q] = s[6 + q];   // s1p0..2, s2p0..2
        }
    } else if (tid < 210) {
        int t = tid - 165;
        int i = 0, j = 0;
        {
            int c = 0;
            for (int ii = 0; ii < 9; ii++)
                for (int jj = ii; jj < 9; jj++) {
                    if (c == t) { i = ii; j = jj; }
                    c++;
                }
        }
        float s[8];
        #pragma unroll
        for (int q = 0; q < 8; q++) s[q] = 0.f;
        auto add2 = [&](int a, int b) {
            int o20 = (a * 9 + b) * 2;   // b20: (9,9,2,1)
            int o21 = o20 * 3;           // b21: (9,9,2,3)
            #pragma unroll
            for (int q = 0; q < 2; q++) s[q] += b20[o20 + q];
            #pragma unroll
            for (int q = 0; q < 6; q++) s[2 + q] += b21[o21 + q];
        };
        if (i == j) add2(i, i); else { add2(i, j); add2(j, i); }
        #pragma unroll
        for (int q = 0; q < 4; q++) {
            tab[G2A_OFF + t * 4 + q] = s[q];         // w20s0, w20s1, s0p0, s0p1
            tab[G2B_OFF + t * 4 + q] = s[4 + q];     // s0p2, s1p0, s1p1, s1p2
        }
    } else if (tid < 219) {
        int a = tid - 210;
        tab[G1A_OFF + a * 2 + 0] = b10[a];           // b10: (9,1,1)
        tab[G1A_OFF + a * 2 + 1] = b11[a * 3 + 0];   // b11: (9,1,3)
        tab[G1B_OFF + a * 2 + 0] = b11[a * 3 + 1];
        tab[G1B_OFF + a * 2 + 1] = b11[a * 3 + 2];
    }
}

// ---------------- main: node-pair per block, q-split across wave pairs ----------------
// 1024 blocks x 256 threads. Each block handles TWO nodes; each thread computes
// one mul (m) for BOTH nodes. The per-wave scalar coefficient stream (SMEM,
// best of the three pipes tested: SMEM~35us / LDS~43us r8 / VMEM~75us r4) is
// amortized 2x: each fetched c[q] feeds 12 FMA (2 nodes x 6 q) instead of 6.
// Waves 0-1: half A of outputs; waves 2-3: half B (readfirstlane-pinned hs,
// round-4 lesson). Natural VGPR allocation (256,2) -- round-2 spill lesson.
__global__ __launch_bounds__(NTH, 2) void mace_sc_kernel(
    const float* __restrict__ nf, const int* __restrict__ spec,
    const float* __restrict__ w10, const float* __restrict__ w11,
    const float* __restrict__ w20, const float* __restrict__ w21,
    const float* __restrict__ w30, const float* __restrict__ w31,
    const float* __restrict__ tab, float* __restrict__ out)
{
    __shared__ float part[2][4][128];   // half-B partial acc, [r][p][m]

    const int node0 = blockIdx.x * 2;
    const int tid   = threadIdx.x;
    const int m     = tid & 127;
    // wave-uniform half index, pinned to SGPR
    const int hs    = __builtin_amdgcn_readfirstlane(tid >> 7);

    float f[2][9];
    #pragma unroll
    for (int r = 0; r < 2; r++) {
        const float* nfp = nf + (node0 + r) * 1152;
        f[r][0] = nfp[m];                                               // 0e
        #pragma unroll
        for (int j = 0; j < 3; j++) f[r][1 + j] = nfp[128 + m * 3 + j]; // 1o
        #pragma unroll
        for (int j = 0; j < 5; j++) f[r][4 + j] = nfp[512 + m * 5 + j]; // 2e
    }
    const int z0 = spec[node0];                 // block-uniform -> scalar
    const int z1 = spec[node0 + 1];

    float acc[2][4];
    #pragma unroll
    for (int r = 0; r < 2; r++)
        #pragma unroll
        for (int p = 0; p < 4; p++) acc[r][p] = 0.f;

    // ---- nu = 3 ----  (fully unrolled; shared c[q] feeds both nodes)
    {
        const float* g3 = tab + (hs ? G3B_OFF : G3A_OFF);   // scalar base
        float t3[2][6];
        #pragma unroll
        for (int r = 0; r < 2; r++)
            #pragma unroll
            for (int q = 0; q < 6; q++) t3[r][q] = 0.f;

        int t = 0;
        #pragma unroll
        for (int i = 0; i < 9; i++) {
            #pragma unroll
            for (int j = i; j < 9; j++) {
                const float fij0 = f[0][i] * f[0][j];
                const float fij1 = f[1][i] * f[1][j];
                #pragma unroll
                for (int k = j; k < 9; k++) {
                    const float* c = &g3[t * 6];
                    const float m30 = fij0 * f[0][k];
                    const float m31 = fij1 * f[1][k];
                    #pragma unroll
                    for (int q = 0; q < 6; q++) {
                        t3[0][q] = fmaf(c[q], m30, t3[0][q]);
                        t3[1][q] = fmaf(c[q], m31, t3[1][q]);
                    }
                    t++;
                }
            }
        }
        #pragma unroll
        for (int r = 0; r < 2; r++) {
            const int z = r ? z1 : z0;
            if (hs == 0) {
                const float* w30z = w30 + z * 384;   // (10,3,128)
                const float* w31z = w31 + z * 384;
                #pragma unroll
                for (int s = 0; s < 3; s++)
                    acc[r][0] = fmaf(w30z[s * 128 + m], t3[r][s], acc[r][0]);
                const float wu = w31z[m];            // s = 0
                acc[r][1] = fmaf(wu, t3[r][3], acc[r][1]);
                acc[r][2] = fmaf(wu, t3[r][4], acc[r][2]);
                acc[r][3] = fmaf(wu, t3[r][5], acc[r][3]);
            } else {
                const float* w31z = w31 + z * 384;
                const float wu1 = w31z[128 + m];     // s = 1
                const float wu2 = w31z[256 + m];     // s = 2
                acc[r][1] = fmaf(wu1, t3[r][0], acc[r][1]);
                acc[r][2] = fmaf(wu1, t3[r][1], acc[r][2]);
                acc[r][3] = fmaf(wu1, t3[r][2], acc[r][3]);
                acc[r][1] = fmaf(wu2, t3[r][3], acc[r][1]);
                acc[r][2] = fmaf(wu2, t3[r][4], acc[r][2]);
                acc[r][3] = fmaf(wu2, t3[r][5], acc[r][3]);
            }
        }
    }

    // ---- nu = 2 ----
    {
        const float* g2 = tab + (hs ? G2B_OFF : G2A_OFF);   // scalar base
        float t2[2][4];
        #pragma unroll
        for (int r = 0; r < 2; r++)
            #pragma unroll
            for (int q = 0; q < 4; q++) t2[r][q] = 0.f;

        int t = 0;
        #pragma unroll
        for (int i = 0; i < 9; i++) {
            #pragma unroll
            for (int j = i; j < 9; j++) {
                const float* c = &g2[t * 4];
                const float m20 = f[0][i] * f[0][j];
                const float m21 = f[1][i] * f[1][j];
                #pragma unroll
                for (int q = 0; q < 4; q++) {
                    t2[0][q] = fmaf(c[q], m20, t2[0][q]);
                    t2[1][q] = fmaf(c[q], m21, t2[1][q]);
                }
                t++;
            }
        }
        #pragma unroll
        for (int r = 0; r < 2; r++) {
            const int z = r ? z1 : z0;
            if (hs == 0) {
                const float* w20z = w20 + z * 256;   // (10,2,128)
                const float* w21z = w21 + z * 256;
                acc[r][0] = fmaf(w20z[m],       t2[r][0], acc[r][0]);
                acc[r][0] = fmaf(w20z[128 + m], t2[r][1], acc[r][0]);
                const float wu = w21z[m];            // s = 0 -> p0,p1
                acc[r][1] = fmaf(wu, t2[r][2], acc[r][1]);
                acc[r][2] = fmaf(wu, t2[r][3], acc[r][2]);
            } else {
                const float* w21z = w21 + z * 256;
                const float wu0 = w21z[m];           // s = 0 -> p2
                acc[r][3] = fmaf(wu0, t2[r][0], acc[r][3]);
                const float wu1 = w21z[128 + m];     // s = 1 -> p0..2
                acc[r][1] = fmaf(wu1, t2[r][1], acc[r][1]);
                acc[r][2] = fmaf(wu1, t2[r][2], acc[r][2]);
                acc[r][3] = fmaf(wu1, t2[r][3], acc[r][3]);
            }
        }
    }

    // ---- nu = 1 ----
    {
        const float* g1 = tab + (hs ? G1B_OFF : G1A_OFF);   // scalar base
        float t1[2][2];
        #pragma unroll
        for (int r = 0; r < 2; r++) { t1[r][0] = 0.f; t1[r][1] = 0.f; }
        #pragma unroll
        for (int a = 0; a < 9; a++) {
            const float* c = &g1[a * 2];
            #pragma unroll
            for (int r = 0; r < 2; r++) {
                t1[r][0] = fmaf(c[0], f[r][a], t1[r][0]);
                t1[r][1] = fmaf(c[1], f[r][a], t1[r][1]);
            }
        }
        #pragma unroll
        for (int r = 0; r < 2; r++) {
            const int z = r ? z1 : z0;
            if (hs == 0) {
                acc[r][0] = fmaf(w10[z * 128 + m], t1[r][0], acc[r][0]);
                acc[r][1] = fmaf(w11[z * 128 + m], t1[r][1], acc[r][1]);
            } else {
                const float wu = w11[z * 128 + m];
                acc[r][2] = fmaf(wu, t1[r][0], acc[r][2]);
                acc[r][3] = fmaf(wu, t1[r][1], acc[r][3]);
            }
        }
    }

    // ---- combine halves via LDS, store from half-A waves ----
    if (hs == 1) {
        #pragma unroll
        for (int r = 0; r < 2; r++)
            #pragma unroll
            for (int p = 0; p < 4; p++) part[r][p][m] = acc[r][p];
    }
    __syncthreads();
    if (hs == 0) {
        #pragma unroll
        for (int r = 0; r < 2; r++) {
            #pragma unroll
            for (int p = 0; p < 4; p++) acc[r][p] += part[r][p][m];
            float* op = out + (node0 + r) * 512;
            op[m] = acc[r][0];
            #pragma unroll
            for (int p = 0; p < 3; p++) op[128 + m * 3 + p] = acc[r][1 + p];
        }
    }
}

extern "C" void kernel_launch(void* const* d_in, const int* in_sizes, int n_in,
                              void* d_out, int out_size, void* d_ws, size_t ws_size,
                              hipStream_t stream) {
    // setup_inputs() dict order is INTERLEAVED: node_feats, species,
    // b10, w10, b11, w11, b20, w20, b21, w21, b30, w30, b31, w31
    const float* nf  = (const float*)d_in[0];
    const int* spec  = (const int*)d_in[1];
    const float* b10 = (const float*)d_in[2];
    const float* w10 = (const float*)d_in[3];
    const float* b11 = (const float*)d_in[4];
    const float* w11 = (const float*)d_in[5];
    const float* b20 = (const float*)d_in[6];
    const float* w20 = (const float*)d_in[7];
    const float* b21 = (const float*)d_in[8];
    const float* w21 = (const float*)d_in[9];
    const float* b30 = (const float*)d_in[10];
    const float* w30 = (const float*)d_in[11];
    const float* b31 = (const float*)d_in[12];
    const float* w31 = (const float*)d_in[13];
    float* out = (float*)d_out;
    float* tab = (float*)d_ws;                 // needs TAB_FLOATS*4 = 9.5 KB

    mace_prep<<<1, 256, 0, stream>>>(b10, b11, b20, b21, b30, b31, tab);

    // one block per NODE PAIR; waves 0-1 = half A, waves 2-3 = half B
    mace_sc_kernel<<<N_NODES / 2, NTH, 0, stream>>>(
        nf, spec, w10, w11, w20, w21, w30, w31, tab, out);
}

// Round 10
// 111.175 us; speedup vs baseline: 1.5331x; 1.5331x over previous
//
#include <hip/hip_runtime.h>

#define NTH 256
#define N_NODES 2048

// Split symmetrized coefficient tables (workspace floats).
// Half A (waves 0-1): nu3 {s0,s1,s2, s0p0,s0p1,s0p2}, nu2 {w20s0,w20s1, s0p0,s0p1},
//                     nu1 {b10, b11p0}
// Half B (waves 2-3): nu3 {s1p0..s1p2, s2p0..s2p2},   nu2 {s0p2, s1p0,s1p1,s1p2},
//                     nu1 {b11p1, b11p2}
#define G3A_OFF 0      // 165*6
#define G3B_OFF 990    // 165*6
#define G2A_OFF 1980   // 45*4
#define G2B_OFF 2160   // 45*4
#define G1A_OFF 2340   // 9*2
#define G1B_OFF 2358   // 9*2
#define TAB_FLOATS 2376

// ---------------- prep: build split symmetrized tables into global ws ----------------
__global__ void mace_prep(
    const float* __restrict__ b10, const float* __restrict__ b11,
    const float* __restrict__ b20, const float* __restrict__ b21,
    const float* __restrict__ b30, const float* __restrict__ b31,
    float* __restrict__ tab)
{
    const int tid = threadIdx.x;
    if (tid < 165) {
        // decode multiset rank -> (i<=j<=k)
        int i = 0, j = 0, k = 0;
        {
            int c = 0;
            for (int ii = 0; ii < 9; ii++)
                for (int jj = ii; jj < 9; jj++)
                    for (int kk = jj; kk < 9; kk++) {
                        if (c == tid) { i = ii; j = jj; k = kk; }
                        c++;
                    }
        }
        float s[12];
        #pragma unroll
        for (int q = 0; q < 12; q++) s[q] = 0.f;
        auto add3 = [&](int a, int b, int c2) {
            int o30 = ((a * 9 + b) * 9 + c2) * 3;   // b30: (9,9,9,3,1)
            int o31 = o30 * 3;                      // b31: (9,9,9,3,3)
            #pragma unroll
            for (int q = 0; q < 3; q++) s[q] += b30[o30 + q];
            #pragma unroll
            for (int q = 0; q < 9; q++) s[3 + q] += b31[o31 + q];
        };
        if (i == j && j == k) { add3(i, j, k); }
        else if (i == j)      { add3(i, i, k); add3(i, k, i); add3(k, i, i); }
        else if (j == k)      { add3(i, j, j); add3(j, i, j); add3(j, j, i); }
        else { add3(i,j,k); add3(i,k,j); add3(j,i,k); add3(j,k,i); add3(k,i,j); add3(k,j,i); }
        #pragma unroll
        for (int q = 0; q < 6; q++) {
            tab[G3A_OFF + tid * 6 + q] = s[q];       // s0..2, s0p0..2
            tab[G3B_OFF + tid * 6 + q] = s[6 + q];   // s1p0..2, s2p0..2
        }
    } else if (tid < 210) {
        int t = tid - 165;
        int i = 0, j = 0;
        {
            int c = 0;
            for (int ii = 0; ii < 9; ii++)
                for (int jj = ii; jj < 9; jj++) {
                    if (c == t) { i = ii; j = jj; }
                    c++;
                }
        }
        float s[8];
        #pragma unroll
        for (int q = 0; q < 8; q++) s[q] = 0.f;
        auto add2 = [&](int a, int b) {
            int o20 = (a * 9 + b) * 2;   // b20: (9,9,2,1)
            int o21 = o20 * 3;           // b21: (9,9,2,3)
            #pragma unroll
            for (int q = 0; q < 2; q++) s[q] += b20[o20 + q];
            #pragma unroll
            for (int q = 0; q < 6; q++) s[2 + q] += b21[o21 + q];
        };
        if (i == j) add2(i, i); else { add2(i, j); add2(j, i); }
        #pragma unroll
        for (int q = 0; q < 4; q++) {
            tab[G2A_OFF + t * 4 + q] = s[q];         // w20s0, w20s1, s0p0, s0p1
            tab[G2B_OFF + t * 4 + q] = s[4 + q];     // s0p2, s1p0, s1p1, s1p2
        }
    } else if (tid < 219) {
        int a = tid - 210;
        tab[G1A_OFF + a * 2 + 0] = b10[a];           // b10: (9,1,1)
        tab[G1A_OFF + a * 2 + 1] = b11[a * 3 + 0];   // b11: (9,1,3)
        tab[G1B_OFF + a * 2 + 0] = b11[a * 3 + 1];
        tab[G1B_OFF + a * 2 + 1] = b11[a * 3 + 2];
    }
}

// ---------------- main: one block per node, q-split, ROW-BATCHED s_loads ----------------
// Structure = round 5/7 (best measured). Single change: each (i,j) row's entire
// coefficient block (up to 54 floats) is staged into a statically-indexed local
// array (uniform -> SGPRs) BEFORE any FMA of that row. SMEM returns out-of-order,
// so every use forces a FULL lgkmcnt(0) drain -- the only way to cut stall time
// is fewer, bigger batches: 1 drain per 9 multisets (108 FMA) instead of the
// compiler's pressure-default batching. Working set unchanged (SGPRs, not VGPRs;
// round-2/9 lesson: VGPR growth = spill catastrophe).
__global__ __launch_bounds__(NTH, 2) void mace_sc_kernel(
    const float* __restrict__ nf, const int* __restrict__ spec,
    const float* __restrict__ w10, const float* __restrict__ w11,
    const float* __restrict__ w20, const float* __restrict__ w21,
    const float* __restrict__ w30, const float* __restrict__ w31,
    const float* __restrict__ tab, float* __restrict__ out)
{
    __shared__ float part[4][128];   // half-B partial acc, [p][m]

    const int node = blockIdx.x;
    const int tid  = threadIdx.x;
    const int m    = tid & 127;
    // wave-uniform half index, pinned to SGPR (round-4 lesson)
    const int hs   = __builtin_amdgcn_readfirstlane(tid >> 7);

    const float* nfp = nf + node * 1152;
    float f[9];
    f[0] = nfp[m];                                                  // 0e block
    #pragma unroll
    for (int j = 0; j < 3; j++) f[1 + j] = nfp[128 + m * 3 + j];    // 1o block
    #pragma unroll
    for (int j = 0; j < 5; j++) f[4 + j] = nfp[512 + m * 5 + j];    // 2e block

    const int z = spec[node];                   // block-uniform -> scalar

    float acc[4];
    #pragma unroll
    for (int p = 0; p < 4; p++) acc[p] = 0.f;

    // ---- nu = 3 ----  (row-batched: stage 6*(9-j) coeffs, then FMA the row)
    {
        const float* g3 = tab + (hs ? G3B_OFF : G3A_OFF);   // scalar base
        float t3[6];
        #pragma unroll
        for (int q = 0; q < 6; q++) t3[q] = 0.f;

        int t = 0;
        #pragma unroll
        for (int i = 0; i < 9; i++) {
            #pragma unroll
            for (int j = i; j < 9; j++) {
                const int len = 9 - j;           // multisets in this (i,j) row
                float cc[54];                    // 6*len used; static indexing only
                #pragma unroll
                for (int q = 0; q < 54; q++) {
                    if (q < 6 * len) cc[q] = g3[t * 6 + q];   // uniform -> s_load
                }
                const float fij = f[i] * f[j];
                #pragma unroll
                for (int kk = 0; kk < 9; kk++) {
                    if (kk < len) {
                        const float m3 = fij * f[j + kk];
                        #pragma unroll
                        for (int q = 0; q < 6; q++)
                            t3[q] = fmaf(cc[kk * 6 + q], m3, t3[q]);
                    }
                }
                t += len;
            }
        }
        if (hs == 0) {
            const float* w30z = w30 + z * 384;   // (10,3,128)
            const float* w31z = w31 + z * 384;
            #pragma unroll
            for (int s = 0; s < 3; s++)
                acc[0] = fmaf(w30z[s * 128 + m], t3[s], acc[0]);
            const float wu = w31z[m];            // s = 0
            acc[1] = fmaf(wu, t3[3], acc[1]);
            acc[2] = fmaf(wu, t3[4], acc[2]);
            acc[3] = fmaf(wu, t3[5], acc[3]);
        } else {
            const float* w31z = w31 + z * 384;
            const float wu1 = w31z[128 + m];     // s = 1
            const float wu2 = w31z[256 + m];     // s = 2
            acc[1] = fmaf(wu1, t3[0], acc[1]);
            acc[2] = fmaf(wu1, t3[1], acc[2]);
            acc[3] = fmaf(wu1, t3[2], acc[3]);
            acc[1] = fmaf(wu2, t3[3], acc[1]);
            acc[2] = fmaf(wu2, t3[4], acc[2]);
            acc[3] = fmaf(wu2, t3[5], acc[3]);
        }
    }

    // ---- nu = 2 ----  (row-batched per i: stage 4*(9-i) coeffs, then FMA)
    {
        const float* g2 = tab + (hs ? G2B_OFF : G2A_OFF);   // scalar base
        float t2[4];
        #pragma unroll
        for (int q = 0; q < 4; q++) t2[q] = 0.f;

        int t = 0;
        #pragma unroll
        for (int i = 0; i < 9; i++) {
            const int len = 9 - i;
            float cc[36];
            #pragma unroll
            for (int q = 0; q < 36; q++) {
                if (q < 4 * len) cc[q] = g2[t * 4 + q];       // uniform -> s_load
            }
            #pragma unroll
            for (int jj = 0; jj < 9; jj++) {
                if (jj < len) {
                    const float m2 = f[i] * f[i + jj];
                    #pragma unroll
                    for (int q = 0; q < 4; q++)
                        t2[q] = fmaf(cc[jj * 4 + q], m2, t2[q]);
                }
            }
            t += len;
        }
        if (hs == 0) {
            const float* w20z = w20 + z * 256;   // (10,2,128)
            const float* w21z = w21 + z * 256;
            acc[0] = fmaf(w20z[m],       t2[0], acc[0]);
            acc[0] = fmaf(w20z[128 + m], t2[1], acc[0]);
            const float wu = w21z[m];            // s = 0 -> p0,p1
            acc[1] = fmaf(wu, t2[2], acc[1]);
            acc[2] = fmaf(wu, t2[3], acc[2]);
        } else {
            const float* w21z = w21 + z * 256;
            const float wu0 = w21z[m];           // s = 0 -> p2
            acc[3] = fmaf(wu0, t2[0], acc[3]);
            const float wu1 = w21z[128 + m];     // s = 1 -> p0..2
            acc[1] = fmaf(wu1, t2[1], acc[1]);
            acc[2] = fmaf(wu1, t2[2], acc[2]);
            acc[3] = fmaf(wu1, t2[3], acc[3]);
        }
    }

    // ---- nu = 1 ----  (single 18-float batch)
    {
        const float* g1 = tab + (hs ? G1B_OFF : G1A_OFF);   // scalar base
        float cc[18];
        #pragma unroll
        for (int q = 0; q < 18; q++) cc[q] = g1[q];          // uniform -> s_load
        float t1[2];
        t1[0] = 0.f; t1[1] = 0.f;
        #pragma unroll
        for (int a = 0; a < 9; a++) {
            t1[0] = fmaf(cc[a * 2 + 0], f[a], t1[0]);
            t1[1] = fmaf(cc[a * 2 + 1], f[a], t1[1]);
        }
        if (hs == 0) {
            acc[0] = fmaf(w10[z * 128 + m], t1[0], acc[0]);
            acc[1] = fmaf(w11[z * 128 + m], t1[1], acc[1]);
        } else {
            const float wu = w11[z * 128 + m];
            acc[2] = fmaf(wu, t1[0], acc[2]);
            acc[3] = fmaf(wu, t1[1], acc[3]);
        }
    }

    // ---- combine halves via LDS, store from half-A waves ----
    if (hs == 1) {
        #pragma unroll
        for (int p = 0; p < 4; p++) part[p][m] = acc[p];
    }
    __syncthreads();
    if (hs == 0) {
        #pragma unroll
        for (int p = 0; p < 4; p++) acc[p] += part[p][m];
        float* op = out + node * 512;
        op[m] = acc[0];
        #pragma unroll
        for (int p = 0; p < 3; p++) op[128 + m * 3 + p] = acc[1 + p];
    }
}

extern "C" void kernel_launch(void* const* d_in, const int* in_sizes, int n_in,
                              void* d_out, int out_size, void* d_ws, size_t ws_size,
                              hipStream_t stream) {
    // setup_inputs() dict order is INTERLEAVED: node_feats, species,
    // b10, w10, b11, w11, b20, w20, b21, w21, b30, w30, b31, w31
    const float* nf  = (const float*)d_in[0];
    const int* spec  = (const int*)d_in[1];
    const float* b10 = (const float*)d_in[2];
    const float* w10 = (const float*)d_in[3];
    const float* b11 = (const float*)d_in[4];
    const float* w11 = (const float*)d_in[5];
    const float* b20 = (const float*)d_in[6];
    const float* w20 = (const float*)d_in[7];
    const float* b21 = (const float*)d_in[8];
    const float* w21 = (const float*)d_in[9];
    const float* b30 = (const float*)d_in[10];
    const float* w30 = (const float*)d_in[11];
    const float* b31 = (const float*)d_in[12];
    const float* w31 = (const float*)d_in[13];
    float* out = (float*)d_out;
    float* tab = (float*)d_ws;                 // needs TAB_FLOATS*4 = 9.5 KB

    mace_prep<<<1, 256, 0, stream>>>(b10, b11, b20, b21, b30, b31, tab);

    // one block per node; waves 0-1 = half A, waves 2-3 = half B
    mace_sc_kernel<<<N_NODES, NTH, 0, stream>>>(
        nf, spec, w10, w11, w20, w21, w30, w31, tab, out);
}